// Round 1
// baseline (96.450 us; speedup 1.0000x reference)
//
#include <hip/hip_runtime.h>

#define WAVE   64
#define DLEN   4096
#define EPT    (DLEN / WAVE)   // 64 elements per lane
#define NCHUNK (EPT / 4)       // 16 float4 chunks per lane
#define NITER  50

__global__ __launch_bounds__(WAVE, 4)
void entmax_bisect_kernel(const float* __restrict__ scores,
                          const int* __restrict__ mask,
                          const float* __restrict__ alpha_ptr,
                          float* __restrict__ out)
{
    const int row  = blockIdx.x;
    const int lane = threadIdx.x;

    const float NEG_INF = -__builtin_inff();

    const float alpha = fmaxf(alpha_ptr[0], 1.001f);
    const float am1   = alpha - 1.0f;
    const float expo  = 1.0f / am1;
    const bool  sq    = (expo == 2.0f);   // alpha == 1.5 fast path

    const size_t base = (size_t)row * DLEN;
    const float* srow = scores + base;
    const int*   mrow = mask + base;

    // ---- load row into registers, apply mask + scale, track max ----
    float xs[EPT];
    float rmax = NEG_INF;
#pragma unroll
    for (int c = 0; c < NCHUNK; ++c) {
        const int idx = c * (WAVE * 4) + lane * 4;
        const float4 s = *reinterpret_cast<const float4*>(srow + idx);
        const int4   m = *reinterpret_cast<const int4*>(mrow + idx);
        const float x0 = m.x ? s.x * am1 : NEG_INF;
        const float x1 = m.y ? s.y * am1 : NEG_INF;
        const float x2 = m.z ? s.z * am1 : NEG_INF;
        const float x3 = m.w ? s.w * am1 : NEG_INF;
        xs[c*4+0] = x0; xs[c*4+1] = x1; xs[c*4+2] = x2; xs[c*4+3] = x3;
        rmax = fmaxf(rmax, fmaxf(fmaxf(x0, x1), fmaxf(x2, x3)));
    }
#pragma unroll
    for (int off = 32; off; off >>= 1)
        rmax = fmaxf(rmax, __shfl_xor(rmax, off));

    float tau_lo = rmax - 1.0f;                       // _gp(1, alpha) = 1
    const float tau_hi = rmax - exp2f(-12.0f * am1);  // (1/4096)^(alpha-1), exact

    float tau_m = tau_lo;
    float sum_m = 1.0f;

    if (sq) {
        // ---------- exponent == 2 fast path: p = max(z,0)^2 ----------
        auto rsum = [&](float tau) -> float {
            float s0 = 0.f, s1 = 0.f, s2 = 0.f, s3 = 0.f;
#pragma unroll
            for (int i = 0; i < EPT; i += 4) {
                const float z0 = fmaxf(xs[i+0] - tau, 0.f);
                const float z1 = fmaxf(xs[i+1] - tau, 0.f);
                const float z2 = fmaxf(xs[i+2] - tau, 0.f);
                const float z3 = fmaxf(xs[i+3] - tau, 0.f);
                s0 = fmaf(z0, z0, s0);
                s1 = fmaf(z1, z1, s1);
                s2 = fmaf(z2, z2, s2);
                s3 = fmaf(z3, z3, s3);
            }
            float s = (s0 + s1) + (s2 + s3);
#pragma unroll
            for (int off = 32; off; off >>= 1) s += __shfl_xor(s, off);
            return s;
        };

        const float f_lo = rsum(tau_lo) - 1.0f;
        float dm = tau_hi - tau_lo;
#pragma unroll 1
        for (int it = 0; it < NITER; ++it) {
            dm *= 0.5f;
            tau_m = tau_lo + dm;
            sum_m = rsum(tau_m);
            const float f_m = sum_m - 1.0f;
            tau_lo = (f_m * f_lo >= 0.0f) ? tau_m : tau_lo;
        }

        const float inv = 1.0f / sum_m;
#pragma unroll
        for (int c = 0; c < NCHUNK; ++c) {
            const int idx = c * (WAVE * 4) + lane * 4;
            float4 o; float z;
            z = fmaxf(xs[c*4+0] - tau_m, 0.f); o.x = z * z * inv;
            z = fmaxf(xs[c*4+1] - tau_m, 0.f); o.y = z * z * inv;
            z = fmaxf(xs[c*4+2] - tau_m, 0.f); o.z = z * z * inv;
            z = fmaxf(xs[c*4+3] - tau_m, 0.f); o.w = z * z * inv;
            *reinterpret_cast<float4*>(out + base + idx) = o;
        }
    } else {
        // ---------- general exponent path: p = z^(1/(alpha-1)) ----------
        auto rsum = [&](float tau) -> float {
            float s = 0.f;
#pragma unroll
            for (int i = 0; i < EPT; ++i) {
                const float z = xs[i] - tau;
                s += (z > 0.f) ? powf(z, expo) : 0.f;
            }
#pragma unroll
            for (int off = 32; off; off >>= 1) s += __shfl_xor(s, off);
            return s;
        };

        const float f_lo = rsum(tau_lo) - 1.0f;
        float dm = tau_hi - tau_lo;
#pragma unroll 1
        for (int it = 0; it < NITER; ++it) {
            dm *= 0.5f;
            tau_m = tau_lo + dm;
            sum_m = rsum(tau_m);
            const float f_m = sum_m - 1.0f;
            tau_lo = (f_m * f_lo >= 0.0f) ? tau_m : tau_lo;
        }

        const float inv = 1.0f / sum_m;
#pragma unroll
        for (int c = 0; c < NCHUNK; ++c) {
            const int idx = c * (WAVE * 4) + lane * 4;
            float4 o; float z;
            z = xs[c*4+0] - tau_m; o.x = (z > 0.f) ? powf(z, expo) * inv : 0.f;
            z = xs[c*4+1] - tau_m; o.y = (z > 0.f) ? powf(z, expo) * inv : 0.f;
            z = xs[c*4+2] - tau_m; o.z = (z > 0.f) ? powf(z, expo) * inv : 0.f;
            z = xs[c*4+3] - tau_m; o.w = (z > 0.f) ? powf(z, expo) * inv : 0.f;
            *reinterpret_cast<float4*>(out + base + idx) = o;
        }
    }
}

extern "C" void kernel_launch(void* const* d_in, const int* in_sizes, int n_in,
                              void* d_out, int out_size, void* d_ws, size_t ws_size,
                              hipStream_t stream) {
    const float* scores = (const float*)d_in[0];
    const int*   mask   = (const int*)d_in[1];
    const float* alpha  = (const float*)d_in[2];
    float*       out    = (float*)d_out;
    const int rows = in_sizes[0] / DLEN;
    entmax_bisect_kernel<<<rows, WAVE, 0, stream>>>(scores, mask, alpha, out);
}